// Round 7
// baseline (227.743 us; speedup 1.0000x reference)
//
#include <hip/hip_runtime.h>
#include <hip/hip_bf16.h>
#include <cstdint>
#include <cstddef>

// B=4,G=64,N=256,C=256,HEAD=8,HD=32
// out = softmax((q@wq+bq)(k@wk+bk)^T / sqrt(32)) @ (v@wv+bv) @ wo + bo
// GEMM structure (round 7): 64x64 tile per block, 4 waves x 16 rows.
//   - ALL A-fragment loads issued upfront into distinct regs (counted vmcnt,
//     no WAR hazards, no per-K-step drains).
//   - B (weight) staged ONCE for full K=256 in LDS (round-6 swizzled layout,
//     measured 0 bank conflicts). ONE barrier per block, none in K-loop.
//   - n-siblings of an A-panel placed == mod 8 -> same XCD -> L2 reuse.
// ws (bf16): Qb | Kb | Vb | WT(4x256x256) ; ctx aliases Qb.

typedef __attribute__((ext_vector_type(4))) float f4;
typedef __attribute__((ext_vector_type(8))) short s8;
typedef __attribute__((ext_vector_type(4))) short s4;
typedef unsigned short u16;

#define AS1 __attribute__((address_space(1)))
#define AS3 __attribute__((address_space(3)))

static constexpr int CD = 256;

__device__ __forceinline__ u16 f2bf(float f) {
    __hip_bfloat16 h = __float2bfloat16(f);   // RNE
    return *reinterpret_cast<u16*>(&h);
}

__device__ __forceinline__ void gload_lds16(const void* g, void* l) {
    __builtin_amdgcn_global_load_lds((const AS1 uint32_t*)g, (AS3 uint32_t*)l, 16, 0, 0);
}

// ---------------- prep: WT[n][k] = W[k][n] as bf16; wq pre-scaled by qs ------
__global__ __launch_bounds__(256) void prep_k(const float* __restrict__ wq,
                                              const float* __restrict__ wk,
                                              const float* __restrict__ wv,
                                              const float* __restrict__ wo,
                                              u16* __restrict__ WT, float qs)
{
    const int bx = blockIdx.x;                 // 64 blocks: 4 weights x 16 tiles
    const int wsel = bx >> 4, tl = bx & 15;
    const int k0 = (tl & 3) * 64, n0 = (tl >> 2) * 64;
    const float* W = wsel == 0 ? wq : wsel == 1 ? wk : wsel == 2 ? wv : wo;
    const float scale = wsel == 0 ? qs : 1.0f;
    u16* dst = WT + (size_t)wsel * 65536;
    __shared__ float T[64][65];
    const int t = threadIdx.x;
    const int rr = t >> 4, c0 = (t & 15) * 4;
    #pragma unroll
    for (int i = 0; i < 4; ++i) {
        int r = i * 16 + rr;
        f4 f = *(const f4*)(W + (size_t)(k0 + r) * CD + n0 + c0);
        #pragma unroll
        for (int j = 0; j < 4; ++j) T[c0 + j][r] = f[j] * scale;
    }
    __syncthreads();
    #pragma unroll
    for (int i = 0; i < 4; ++i) {
        int n = i * 16 + rr;
        s4 h;
        #pragma unroll
        for (int j = 0; j < 4; ++j) h[j] = (short)f2bf(T[n][c0 + j]);
        *(s4*)(dst + (size_t)(n0 + n) * CD + k0 + c0) = h;
    }
}

// ---------------- GEMM: Out[m0:+64][n0:+64] = A @ WT^T + bias*escale --------
// d decode: x3=d&7, n0=((d>>3)&3)*64, m0=(((d>>5)<<3)|x3)*64
template<bool A_F32, bool OUT_F32>
__device__ __forceinline__ void gemm_body(const void* __restrict__ Ain,
                                          const u16* __restrict__ Wt,
                                          const float* __restrict__ bias,
                                          float escale, void* __restrict__ Out,
                                          int d)
{
    __shared__ u16 Bs[4][64 * 64];   // 4 K-chunks of 64 cols x 64 k, 32 KB
    const int t = threadIdx.x, lane = t & 63, w = t >> 6;
    const int n0 = ((d >> 3) & 3) * 64;
    const int m0 = (((d >> 5) << 3) | (d & 7)) * 64;
    const int lr = lane & 15, lkg = lane >> 4;
    const int lk = lkg * 8;
    const int bc = lane >> 3, bcol = (lane & 7) * 8;

    const int rowA = m0 + w * 16 + lr;

    // ---- 1. issue ALL A loads upfront (distinct regs -> counted vmcnt) ----
    f4 pa[16];   // fp32 path
    s8 pb[8];    // bf16 path
    if constexpr (A_F32) {
        const float* ap = (const float*)Ain + (size_t)rowA * CD + lk;
        #pragma unroll
        for (int ks = 0; ks < 8; ++ks) {
            pa[2 * ks]     = *(const f4*)(ap + ks * 32);
            pa[2 * ks + 1] = *(const f4*)(ap + ks * 32 + 4);
        }
    } else {
        const u16* ap = (const u16*)Ain + (size_t)rowA * CD + lk;
        #pragma unroll
        for (int ks = 0; ks < 8; ++ks)
            pb[ks] = *(const s8*)(ap + ks * 32);
    }

    // ---- 2. stage B once: full K, round-6 swizzled layout (0 conflicts) ---
    #pragma unroll
    for (int ck = 0; ck < 4; ++ck) {
        #pragma unroll
        for (int j = 0; j < 2; ++j) {
            int c = j * 4 + w;                 // 0..7 (8 rows each)
            int row = c * 8 + bc;              // 0..63 = output col
            int col = bcol ^ ((row & 7) << 3);
            gload_lds16(Wt + (size_t)(n0 + row) * CD + ck * 64 + col,
                        &Bs[ck][c * 512 + lane * 8]);
        }
    }
    __syncthreads();   // single drain; all A loads + B stage complete

    // ---- 3. stall-free compute: 32 MFMAs from regs + LDS ------------------
    f4 acc[4] = {};
    #pragma unroll
    for (int ks = 0; ks < 8; ++ks) {
        s8 a;
        if constexpr (A_F32) {
            #pragma unroll
            for (int i = 0; i < 4; ++i) {
                a[i]     = (short)f2bf(pa[2 * ks][i]);
                a[i + 4] = (short)f2bf(pa[2 * ks + 1][i]);
            }
        } else {
            a = pb[ks];
        }
        const int ck = ks >> 1, kk = (ks & 1) * 32;
        #pragma unroll
        for (int n = 0; n < 4; ++n) {
            int R = n * 16 + lr;
            s8 b = *(const s8*)&Bs[ck][R * 64 + ((kk + lk) ^ ((R & 7) << 3))];
            acc[n] = __builtin_amdgcn_mfma_f32_16x16x32_bf16(a, b, acc[n], 0, 0, 0);
        }
    }

    // ---- 4. epilogue: D[row=(lane>>4)*4+r][col=lane&15] --------------------
    const int orow = lkg * 4;
    #pragma unroll
    for (int n = 0; n < 4; ++n) {
        int col = n0 + n * 16 + lr;
        float bb = bias[col] * escale;
        #pragma unroll
        for (int r = 0; r < 4; ++r) {
            int row = m0 + w * 16 + orow + r;
            float vv = acc[n][r] + bb;
            if constexpr (OUT_F32)
                ((float*)Out)[(size_t)row * CD + col] = vv;
            else
                ((u16*)Out)[(size_t)row * CD + col] = f2bf(vv);
        }
    }
}

__global__ __launch_bounds__(256, 4) void gemmqkv_k(const float* q, const float* k,
        const float* v, const u16* WT, const float* bq, const float* bk,
        const float* bv, float qs, u16* Qb, u16* Kb, u16* Vb)
{
    const int op = blockIdx.x >> 12;     // 4096 blocks per op (4096%8==0)
    const int d  = blockIdx.x & 4095;
    const float* A    = op == 0 ? q  : op == 1 ? k  : v;
    const u16*   Wt   = WT + (size_t)op * 65536;
    const float* bias = op == 0 ? bq : op == 1 ? bk : bv;
    u16*         Out  = op == 0 ? Qb : op == 1 ? Kb : Vb;
    gemm_body<true, false>(A, Wt, bias, op == 0 ? qs : 1.0f, Out, d);
}

__global__ __launch_bounds__(256, 4) void gemmo_k(const u16* Cx, const u16* WT,
                                                  const float* bo, float* out)
{
    gemm_body<false, true>(Cx, WT, bo, 1.0f, out, blockIdx.x);
}

// ---------------- attn: one block per (b,g,h); 4 waves x 64 q-rows ----------
// Q pre-scaled by log2e/sqrt(hd) (folded into Wq) -> softmax via exp2.
__global__ __launch_bounds__(256, 3) void attn_k(const u16* Qb,
                                                 const u16* __restrict__ Kb,
                                                 const u16* __restrict__ Vb,
                                                 u16* Ctx)   // Ctx aliases Qb!
{
    __shared__ u16 Ks[256 * 32];       // swizzled rows of 32 elems, 16 KB
    __shared__ u16 Vt[32][260];        // [d][krow], 16.25 KB
    __shared__ u16 Ps[4][16][132];     // per-wave half-strip, 16.5 KB
    const int d = blockIdx.x;          // h*256 + bg: all h of a (b,g) same XCD
    const int bg = d & 255, h = d >> 8;
    const size_t base = (size_t)bg * (256 * 256) + h * 32;
    const int t = threadIdx.x, lane = t & 63, w = t >> 6;
    const int lr = lane & 15, lk = (lane >> 4) * 8;
    const int orow = (lane >> 4) * 4;

    // stage K (swizzled global_load_lds: slot ^= ((row>>1)&3)<<3)
    #pragma unroll
    for (int j = 0; j < 4; ++j) {
        int c = j * 4 + w;
        int row = c * 16 + (lane >> 2);
        int col = ((lane & 3) * 8) ^ (((row >> 1) & 3) << 3);
        gload_lds16(Kb + base + (size_t)row * CD + col, &Ks[c * 512 + lane * 8]);
    }
    // stage V transposed: each thread one 4x8 block, vectorized s4 column writes
    {
        int n0 = (t >> 2) * 4, c0 = (t & 3) * 8;
        const u16* vp = Vb + base + (size_t)n0 * CD + c0;
        s8 r0 = *(const s8*)(vp);
        s8 r1 = *(const s8*)(vp + CD);
        s8 r2 = *(const s8*)(vp + 2 * CD);
        s8 r3 = *(const s8*)(vp + 3 * CD);
        #pragma unroll
        for (int i = 0; i < 8; ++i) {
            s4 cv = { r0[i], r1[i], r2[i], r3[i] };
            *(s4*)&Vt[c0 + i][n0] = cv;
        }
    }
    // hoist all Q fragments (must precede any Ctx write: Ctx aliases Qb)
    s8 aq[4];
    #pragma unroll
    for (int m = 0; m < 4; ++m)
        aq[m] = *(const s8*)(Qb + base + (size_t)(w * 64 + m * 16 + lr) * CD + lk);

    __syncthreads();

    const int myslot = lk ^ (((lr >> 1) & 3) << 3);
    const f4 zero = {0.f, 0.f, 0.f, 0.f};

    #pragma unroll
    for (int m = 0; m < 4; ++m) {
        // S = Q K^T  (16 q-rows x 256 k)
        f4 s[16];
        #pragma unroll
        for (int j = 0; j < 16; ++j) {
            s8 bk = *(const s8*)&Ks[(j * 16 + lr) * 32 + myslot];
            s[j] = __builtin_amdgcn_mfma_f32_16x16x32_bf16(aq[m], bk, zero, 0, 0, 0);
        }
        // softmax over k (base-2 domain; scale folded into Q)
        float mrow[4] = {-3.0e38f, -3.0e38f, -3.0e38f, -3.0e38f};
        #pragma unroll
        for (int j = 0; j < 16; ++j)
            #pragma unroll
            for (int r = 0; r < 4; ++r) mrow[r] = fmaxf(mrow[r], s[j][r]);
        #pragma unroll
        for (int dd = 1; dd < 16; dd <<= 1)
            #pragma unroll
            for (int r = 0; r < 4; ++r) mrow[r] = fmaxf(mrow[r], __shfl_xor(mrow[r], dd));
        float lsum[4] = {0.f, 0.f, 0.f, 0.f};
        #pragma unroll
        for (int j = 0; j < 16; ++j)
            #pragma unroll
            for (int r = 0; r < 4; ++r) {
                float p = exp2f(s[j][r] - mrow[r]);
                s[j][r] = p;
                lsum[r] += p;
            }
        #pragma unroll
        for (int dd = 1; dd < 16; dd <<= 1)
            #pragma unroll
            for (int r = 0; r < 4; ++r) lsum[r] += __shfl_xor(lsum[r], dd);

        // PV in two halves through per-wave Ps strip (no barrier: wave-local)
        f4 o0 = zero, o1 = zero;
        #pragma unroll
        for (int half = 0; half < 2; ++half) {
            #pragma unroll
            for (int j = 0; j < 8; ++j)
                #pragma unroll
                for (int r = 0; r < 4; ++r)
                    Ps[w][orow + r][j * 16 + lr] = f2bf(s[half * 8 + j][r]);
            #pragma unroll
            for (int kk = 0; kk < 4; ++kk) {
                s8 ap  = *(const s8*)&Ps[w][lr][kk * 32 + lk];
                s8 bv0 = *(const s8*)&Vt[lr][(half * 4 + kk) * 32 + lk];
                s8 bv1 = *(const s8*)&Vt[16 + lr][(half * 4 + kk) * 32 + lk];
                o0 = __builtin_amdgcn_mfma_f32_16x16x32_bf16(ap, bv0, o0, 0, 0, 0);
                o1 = __builtin_amdgcn_mfma_f32_16x16x32_bf16(ap, bv1, o1, 0, 0, 0);
            }
        }
        // store ctx rows (writes into Qb region owned by this wave's rows)
        #pragma unroll
        for (int r = 0; r < 4; ++r) {
            float inv = __builtin_amdgcn_rcpf(lsum[r]);
            int row = w * 64 + m * 16 + orow + r;
            Ctx[base + (size_t)row * CD + lr]      = f2bf(o0[r] * inv);
            Ctx[base + (size_t)row * CD + 16 + lr] = f2bf(o1[r] * inv);
        }
    }
}

extern "C" void kernel_launch(void* const* d_in, const int* in_sizes, int n_in,
                              void* d_out, int out_size, void* d_ws, size_t ws_size,
                              hipStream_t stream) {
    const float* q  = (const float*)d_in[0];
    const float* k  = (const float*)d_in[1];
    const float* v  = (const float*)d_in[2];
    const float* wq = (const float*)d_in[3];
    const float* bq = (const float*)d_in[4];
    const float* wk = (const float*)d_in[5];
    const float* bk = (const float*)d_in[6];
    const float* wv = (const float*)d_in[7];
    const float* bv = (const float*)d_in[8];
    const float* wo = (const float*)d_in[9];
    const float* bo = (const float*)d_in[10];
    float* out = (float*)d_out;

    const size_t E = (size_t)65536 * 256;
    u16* Qb = (u16*)d_ws;
    u16* Kb = Qb + E;
    u16* Vb = Kb + E;
    u16* WT = Vb + E;          // 4*65536 u16 = 512 KB; total ws = 96.5 MB
    u16* Cx = Qb;              // ctx aliases Qb (safe: per-wave hoisted Q reads)

    const float qs = (1.0f / (sqrtf(32.0f) + 1e-8f)) * 1.4426950408889634f;

    prep_k<<<64, 256, 0, stream>>>(wq, wk, wv, wo, WT, qs);
    gemmqkv_k<<<12288, 256, 0, stream>>>(q, k, v, WT, bq, bk, bv, qs, Qb, Kb, Vb);
    attn_k<<<2048, 256, 0, stream>>>(Qb, Kb, Vb, Cx);
    gemmo_k<<<4096, 256, 0, stream>>>(Cx, WT + 3 * 65536, bo, out);
}

// Round 8
// 206.211 us; speedup vs baseline: 1.1044x; 1.1044x over previous
//
#include <hip/hip_runtime.h>
#include <hip/hip_bf16.h>
#include <cstdint>
#include <cstddef>

// B=4,G=64,N=256,C=256,HEAD=8,HD=32
// out = softmax((q@wq+bq)(k@wk+bk)^T / sqrt(32)) @ (v@wv+bv) @ wo + bo
// GEMM (round 8): 64x64 tile, 4 waves x 16 rows, full K=256 staged once.
//   - A: COALESCED loads (1 row = 1KB per instr), reg cvt, XOR-swizzled LDS
//     (wave-private strip -> no barrier needed for A reuse).
//   - B: staged once via global_load_lds (R7 layout, 0 conflicts measured).
//   - ONE __syncthreads per block; K-loop barrier-free from LDS.
//   - XCD decode: 4 n-siblings of an A-panel == mod 8 -> same L2 (R7: 100MB).
// ws (bf16): Qb | Kb | Vb | WT(4x256x256) ; ctx aliases Qb.

typedef __attribute__((ext_vector_type(4))) float f4;
typedef __attribute__((ext_vector_type(8))) short s8;
typedef __attribute__((ext_vector_type(4))) short s4;
typedef unsigned short u16;

#define AS1 __attribute__((address_space(1)))
#define AS3 __attribute__((address_space(3)))

static constexpr int CD = 256;

__device__ __forceinline__ u16 f2bf(float f) {
    __hip_bfloat16 h = __float2bfloat16(f);   // RNE
    return *reinterpret_cast<u16*>(&h);
}

__device__ __forceinline__ void gload_lds16(const void* g, void* l) {
    __builtin_amdgcn_global_load_lds((const AS1 uint32_t*)g, (AS3 uint32_t*)l, 16, 0, 0);
}

// ---------------- prep: WT[n][k] = W[k][n] as bf16; wq pre-scaled by qs ------
__global__ __launch_bounds__(256) void prep_k(const float* __restrict__ wq,
                                              const float* __restrict__ wk,
                                              const float* __restrict__ wv,
                                              const float* __restrict__ wo,
                                              u16* __restrict__ WT, float qs)
{
    const int bx = blockIdx.x;                 // 64 blocks: 4 weights x 16 tiles
    const int wsel = bx >> 4, tl = bx & 15;
    const int k0 = (tl & 3) * 64, n0 = (tl >> 2) * 64;
    const float* W = wsel == 0 ? wq : wsel == 1 ? wk : wsel == 2 ? wv : wo;
    const float scale = wsel == 0 ? qs : 1.0f;
    u16* dst = WT + (size_t)wsel * 65536;
    __shared__ float T[64][65];
    const int t = threadIdx.x;
    const int rr = t >> 4, c0 = (t & 15) * 4;
    #pragma unroll
    for (int i = 0; i < 4; ++i) {
        int r = i * 16 + rr;
        f4 f = *(const f4*)(W + (size_t)(k0 + r) * CD + n0 + c0);
        #pragma unroll
        for (int j = 0; j < 4; ++j) T[c0 + j][r] = f[j] * scale;
    }
    __syncthreads();
    #pragma unroll
    for (int i = 0; i < 4; ++i) {
        int n = i * 16 + rr;
        s4 h;
        #pragma unroll
        for (int j = 0; j < 4; ++j) h[j] = (short)f2bf(T[n][c0 + j]);
        *(s4*)(dst + (size_t)(n0 + n) * CD + k0 + c0) = h;
    }
}

// ---------------- GEMM: Out[m0:+64][n0:+64] = A @ WT^T + bias*escale --------
template<bool A_F32, bool OUT_F32>
__device__ __forceinline__ void gemm_body(const void* __restrict__ Ain,
                                          const u16* __restrict__ Wt,
                                          const float* __restrict__ bias,
                                          float escale, void* __restrict__ Out,
                                          int d)
{
    __shared__ u16 As[64 * 256];     // [row][k], col ^= (row&7)<<3; 32 KB
    __shared__ u16 Bs[4][64 * 64];   // 4 K-chunks, R7 layout; 32 KB
    const int t = threadIdx.x, lane = t & 63, w = t >> 6;
    const int n0 = ((d >> 3) & 3) * 64;
    const int m0 = (((d >> 5) << 3) | (d & 7)) * 64;
    const int lr = lane & 15, lkg = lane >> 4;
    const int bc = lane >> 3, bcol = (lane & 7) * 8;

    // ---- 1. A loads: COALESCED (fp32: one full 1KB row per instruction) ----
    f4 pf[16];
    if constexpr (A_F32) {
        const float* ap = (const float*)Ain + (size_t)(m0 + w * 16) * CD;
        #pragma unroll
        for (int j = 0; j < 16; ++j)
            pf[j] = *(const f4*)(ap + (size_t)j * CD + lane * 4);
    } else {
        // bf16: stage via global_load_lds with pre-swizzled source
        const u16* A = (const u16*)Ain;
        #pragma unroll
        for (int j = 0; j < 8; ++j) {
            int ch = j * 256 + t;            // 2048 chunks of 16B
            int row = ch >> 5, colb = (ch & 31) * 8;
            int col = colb ^ ((row & 7) << 3);
            gload_lds16(A + (size_t)(m0 + row) * CD + col, &As[ch * 8]);
        }
    }

    // ---- 2. B stage: full K once via gload_lds (R7 verbatim) --------------
    #pragma unroll
    for (int ck = 0; ck < 4; ++ck) {
        #pragma unroll
        for (int j = 0; j < 2; ++j) {
            int c = j * 4 + w;
            int row = c * 8 + bc;
            int col = bcol ^ ((row & 7) << 3);
            gload_lds16(Wt + (size_t)(n0 + row) * CD + ck * 64 + col,
                        &Bs[ck][c * 512 + lane * 8]);
        }
    }

    // ---- 3. fp32 path: cvt + swizzled wave-private LDS write --------------
    if constexpr (A_F32) {
        #pragma unroll
        for (int j = 0; j < 16; ++j) {
            int row = w * 16 + j;
            s4 h;
            #pragma unroll
            for (int i = 0; i < 4; ++i) h[i] = (short)f2bf(pf[j][i]);
            *(s4*)&As[row * 256 + ((lane * 4) ^ ((row & 7) << 3))] = h;
        }
    }

    __syncthreads();   // the ONLY barrier: B (+A for bf16) staged

    // ---- 4. barrier-free K-loop: 32 MFMAs from LDS -------------------------
    f4 acc[4] = {};
    #pragma unroll
    for (int ks = 0; ks < 8; ++ks) {
        int arow = w * 16 + lr;
        s8 a = *(const s8*)&As[arow * 256 +
                               ((ks * 32 + lkg * 8) ^ ((arow & 7) << 3))];
        const int ck = ks >> 1, kk = (ks & 1) * 32;
        #pragma unroll
        for (int n = 0; n < 4; ++n) {
            int R = n * 16 + lr;
            s8 b = *(const s8*)&Bs[ck][R * 64 + ((kk + lkg * 8) ^ ((R & 7) << 3))];
            acc[n] = __builtin_amdgcn_mfma_f32_16x16x32_bf16(a, b, acc[n], 0, 0, 0);
        }
    }

    // ---- 5. epilogue: D[row=(lane>>4)*4+r][col=lane&15] --------------------
    const int orow = lkg * 4;
    #pragma unroll
    for (int n = 0; n < 4; ++n) {
        int col = n0 + n * 16 + lr;
        float bb = bias[col] * escale;
        #pragma unroll
        for (int r = 0; r < 4; ++r) {
            int row = m0 + w * 16 + orow + r;
            float vv = acc[n][r] + bb;
            if constexpr (OUT_F32)
                ((float*)Out)[(size_t)row * CD + col] = vv;
            else
                ((u16*)Out)[(size_t)row * CD + col] = f2bf(vv);
        }
    }
}

__global__ __launch_bounds__(256, 2) void gemmqkv_k(const float* q, const float* k,
        const float* v, const u16* WT, const float* bq, const float* bk,
        const float* bv, float qs, u16* Qb, u16* Kb, u16* Vb)
{
    const int op = blockIdx.x >> 12;     // 4096 blocks per op (4096%8==0)
    const int d  = blockIdx.x & 4095;
    const float* A    = op == 0 ? q  : op == 1 ? k  : v;
    const u16*   Wt   = WT + (size_t)op * 65536;
    const float* bias = op == 0 ? bq : op == 1 ? bk : bv;
    u16*         Out  = op == 0 ? Qb : op == 1 ? Kb : Vb;
    gemm_body<true, false>(A, Wt, bias, op == 0 ? qs : 1.0f, Out, d);
}

__global__ __launch_bounds__(256, 2) void gemmo_k(const u16* Cx, const u16* WT,
                                                  const float* bo, float* out)
{
    gemm_body<false, true>(Cx, WT, bo, 1.0f, out, blockIdx.x);
}

// ---------------- attn: one block per (b,g,h); 4 waves x 64 q-rows ----------
// Q pre-scaled by log2e/sqrt(hd) (folded into Wq) -> softmax via exp2.
__global__ __launch_bounds__(256, 3) void attn_k(const u16* Qb,
                                                 const u16* __restrict__ Kb,
                                                 const u16* __restrict__ Vb,
                                                 u16* Ctx)   // Ctx aliases Qb!
{
    __shared__ u16 Ks[256 * 32];       // swizzled rows of 32 elems, 16 KB
    __shared__ u16 Vt[32][260];        // [d][krow], 16.25 KB
    __shared__ u16 Ps[4][16][132];     // per-wave half-strip, 16.5 KB
    const int d = blockIdx.x;          // h*256 + bg: all h of a (b,g) same XCD
    const int bg = d & 255, h = d >> 8;
    const size_t base = (size_t)bg * (256 * 256) + h * 32;
    const int t = threadIdx.x, lane = t & 63, w = t >> 6;
    const int lr = lane & 15, lk = (lane >> 4) * 8;
    const int orow = (lane >> 4) * 4;

    // stage K (swizzled global_load_lds: slot ^= ((row>>1)&3)<<3)
    #pragma unroll
    for (int j = 0; j < 4; ++j) {
        int c = j * 4 + w;
        int row = c * 16 + (lane >> 2);
        int col = ((lane & 3) * 8) ^ (((row >> 1) & 3) << 3);
        gload_lds16(Kb + base + (size_t)row * CD + col, &Ks[c * 512 + lane * 8]);
    }
    // stage V transposed: each thread one 4x8 block, vectorized s4 column writes
    {
        int n0 = (t >> 2) * 4, c0 = (t & 3) * 8;
        const u16* vp = Vb + base + (size_t)n0 * CD + c0;
        s8 r0 = *(const s8*)(vp);
        s8 r1 = *(const s8*)(vp + CD);
        s8 r2 = *(const s8*)(vp + 2 * CD);
        s8 r3 = *(const s8*)(vp + 3 * CD);
        #pragma unroll
        for (int i = 0; i < 8; ++i) {
            s4 cv = { r0[i], r1[i], r2[i], r3[i] };
            *(s4*)&Vt[c0 + i][n0] = cv;
        }
    }
    // hoist all Q fragments (must precede any Ctx write: Ctx aliases Qb)
    s8 aq[4];
    #pragma unroll
    for (int m = 0; m < 4; ++m)
        aq[m] = *(const s8*)(Qb + base + (size_t)(w * 64 + m * 16 + lr) * CD + lk);

    __syncthreads();

    const int myslot = lk ^ (((lr >> 1) & 3) << 3);
    const f4 zero = {0.f, 0.f, 0.f, 0.f};

    #pragma unroll
    for (int m = 0; m < 4; ++m) {
        // S = Q K^T  (16 q-rows x 256 k)
        f4 s[16];
        #pragma unroll
        for (int j = 0; j < 16; ++j) {
            s8 bk = *(const s8*)&Ks[(j * 16 + lr) * 32 + myslot];
            s[j] = __builtin_amdgcn_mfma_f32_16x16x32_bf16(aq[m], bk, zero, 0, 0, 0);
        }
        // softmax over k (base-2 domain; scale folded into Q)
        float mrow[4] = {-3.0e38f, -3.0e38f, -3.0e38f, -3.0e38f};
        #pragma unroll
        for (int j = 0; j < 16; ++j)
            #pragma unroll
            for (int r = 0; r < 4; ++r) mrow[r] = fmaxf(mrow[r], s[j][r]);
        #pragma unroll
        for (int dd = 1; dd < 16; dd <<= 1)
            #pragma unroll
            for (int r = 0; r < 4; ++r) mrow[r] = fmaxf(mrow[r], __shfl_xor(mrow[r], dd));
        float lsum[4] = {0.f, 0.f, 0.f, 0.f};
        #pragma unroll
        for (int j = 0; j < 16; ++j)
            #pragma unroll
            for (int r = 0; r < 4; ++r) {
                float p = exp2f(s[j][r] - mrow[r]);
                s[j][r] = p;
                lsum[r] += p;
            }
        #pragma unroll
        for (int dd = 1; dd < 16; dd <<= 1)
            #pragma unroll
            for (int r = 0; r < 4; ++r) lsum[r] += __shfl_xor(lsum[r], dd);

        // PV in two halves through per-wave Ps strip (no barrier: wave-local)
        f4 o0 = zero, o1 = zero;
        #pragma unroll
        for (int half = 0; half < 2; ++half) {
            #pragma unroll
            for (int j = 0; j < 8; ++j)
                #pragma unroll
                for (int r = 0; r < 4; ++r)
                    Ps[w][orow + r][j * 16 + lr] = f2bf(s[half * 8 + j][r]);
            #pragma unroll
            for (int kk = 0; kk < 4; ++kk) {
                s8 ap  = *(const s8*)&Ps[w][lr][kk * 32 + lk];
                s8 bv0 = *(const s8*)&Vt[lr][(half * 4 + kk) * 32 + lk];
                s8 bv1 = *(const s8*)&Vt[16 + lr][(half * 4 + kk) * 32 + lk];
                o0 = __builtin_amdgcn_mfma_f32_16x16x32_bf16(ap, bv0, o0, 0, 0, 0);
                o1 = __builtin_amdgcn_mfma_f32_16x16x32_bf16(ap, bv1, o1, 0, 0, 0);
            }
        }
        // store ctx rows (writes into Qb region owned by this wave's rows)
        #pragma unroll
        for (int r = 0; r < 4; ++r) {
            float inv = __builtin_amdgcn_rcpf(lsum[r]);
            int row = w * 64 + m * 16 + orow + r;
            Ctx[base + (size_t)row * CD + lr]      = f2bf(o0[r] * inv);
            Ctx[base + (size_t)row * CD + 16 + lr] = f2bf(o1[r] * inv);
        }
    }
}

extern "C" void kernel_launch(void* const* d_in, const int* in_sizes, int n_in,
                              void* d_out, int out_size, void* d_ws, size_t ws_size,
                              hipStream_t stream) {
    const float* q  = (const float*)d_in[0];
    const float* k  = (const float*)d_in[1];
    const float* v  = (const float*)d_in[2];
    const float* wq = (const float*)d_in[3];
    const float* bq = (const float*)d_in[4];
    const float* wk = (const float*)d_in[5];
    const float* bk = (const float*)d_in[6];
    const float* wv = (const float*)d_in[7];
    const float* bv = (const float*)d_in[8];
    const float* wo = (const float*)d_in[9];
    const float* bo = (const float*)d_in[10];
    float* out = (float*)d_out;

    const size_t E = (size_t)65536 * 256;
    u16* Qb = (u16*)d_ws;
    u16* Kb = Qb + E;
    u16* Vb = Kb + E;
    u16* WT = Vb + E;          // 4*65536 u16 = 512 KB; total ws = 96.5 MB
    u16* Cx = Qb;              // ctx aliases Qb (safe: per-wave hoisted Q reads)

    const float qs = (1.0f / (sqrtf(32.0f) + 1e-8f)) * 1.4426950408889634f;

    prep_k<<<64, 256, 0, stream>>>(wq, wk, wv, wo, WT, qs);
    gemmqkv_k<<<12288, 256, 0, stream>>>(q, k, v, WT, bq, bk, bv, qs, Qb, Kb, Vb);
    attn_k<<<2048, 256, 0, stream>>>(Qb, Kb, Vb, Cx);
    gemmo_k<<<4096, 256, 0, stream>>>(Cx, WT + 3 * 65536, bo, out);
}